// Round 2
// 227.775 us; speedup vs baseline: 1.1156x; 1.1156x over previous
//
#include <hip/hip_runtime.h>

#define N_NODES 100000
#define N_EDGES 1600000
#define D 128
#define N_STRIPS (N_NODES / 32)     // 3125

#define BSH   9                     // coarse bucket = col >> 9 (512 nodes/bucket)
#define NBKT  196                   // ceil(100000 / 512)
#define P_BLK 160                   // partition blocks; EPB = 10000 exactly
#define EPB   (N_EDGES / P_BLK)

typedef __bf16 bf16x4 __attribute__((ext_vector_type(4)));
typedef __bf16 bf16x8 __attribute__((ext_vector_type(8)));
typedef float  f32x4  __attribute__((ext_vector_type(4)));

// ---- P1 fused: blocks 0..P_BLK-1 build coarse histogram; block P_BLK casts W ----
__global__ __launch_bounds__(1024) void k_prep(const int* __restrict__ col,
                                               const float4* __restrict__ w4,
                                               int* __restrict__ bhist,
                                               bf16x4* __restrict__ wb4) {
    int tid = threadIdx.x, b = blockIdx.x;
    if (b == P_BLK) {                      // cast W -> bf16 (4096 float4)
        for (int i = tid; i < (D * D) / 4; i += 1024) {
            float4 u = w4[i];
            bf16x4 p;
            p[0] = (__bf16)u.x; p[1] = (__bf16)u.y;
            p[2] = (__bf16)u.z; p[3] = (__bf16)u.w;
            wb4[i] = p;
        }
        return;
    }
    __shared__ int lh[NBKT];
    if (tid < NBKT) lh[tid] = 0;
    __syncthreads();
    int e0 = b * EPB;
    for (int e = e0 + tid; e < e0 + EPB; e += 1024)
        atomicAdd(&lh[col[e] >> BSH], 1);
    __syncthreads();
    if (tid < NBKT) bhist[tid * P_BLK + b] = lh[tid];
}

// ---- P2a: per-bucket exclusive scan over the 160 block counts (in place) ----
__global__ __launch_bounds__(256) void k_bscan(int* __restrict__ bhist,
                                               int* __restrict__ gtot) {
    __shared__ int buf[256];
    int k = blockIdx.x, t = threadIdx.x;
    int v = (t < P_BLK) ? bhist[k * P_BLK + t] : 0;
    buf[t] = v;
    __syncthreads();
    for (int off = 1; off < 256; off <<= 1) {
        int u = (t >= off) ? buf[t - off] : 0;
        __syncthreads();
        buf[t] += u;
        __syncthreads();
    }
    if (t < P_BLK) bhist[k * P_BLK + t] = buf[t] - v;   // exclusive
    if (t == 255) gtot[k] = buf[255];
}

// ---- P2b: exclusive scan of bucket totals -> gstart ----
__global__ __launch_bounds__(256) void k_gscan(const int* __restrict__ gtot,
                                               int* __restrict__ gstart) {
    __shared__ int buf[256];
    int t = threadIdx.x;
    int v = (t < NBKT) ? gtot[t] : 0;
    buf[t] = v;
    __syncthreads();
    for (int off = 1; off < 256; off <<= 1) {
        int u = (t >= off) ? buf[t - off] : 0;
        __syncthreads();
        buf[t] += u;
        __syncthreads();
    }
    if (t < NBKT) gstart[t] = buf[t] - v;
}

// ---- P3: direct scatter; per-block LDS cursors, zero global atomics ----
__global__ __launch_bounds__(1024) void k_cscatter(const int* __restrict__ row,
                                                   const int* __restrict__ col,
                                                   const int* __restrict__ bhist,
                                                   const int* __restrict__ gstart,
                                                   unsigned* __restrict__ grec) {
    __shared__ int cur[NBKT];
    int b = blockIdx.x, t = threadIdx.x;
    if (t < NBKT) cur[t] = gstart[t] + bhist[t * P_BLK + b];
    __syncthreads();
    int e0 = b * EPB;
    for (int e = e0 + t; e < e0 + EPB; e += 1024) {
        int c = col[e];
        unsigned rec = ((unsigned)row[e] << BSH) | (unsigned)(c & ((1 << BSH) - 1));
        int pos = atomicAdd(&cur[c >> BSH], 1);
        grec[pos] = rec;
    }
}

// ---- P4: per-bucket fine sort in LDS; emits deg/dis/start/srcs ----
__global__ __launch_bounds__(1024) void k_fine(const unsigned* __restrict__ grec,
                                               const int* __restrict__ gtot,
                                               const int* __restrict__ gstart,
                                               int* __restrict__ deg,
                                               float* __restrict__ dis,
                                               int* __restrict__ start,
                                               int* __restrict__ srcs) {
    __shared__ int fh[512];
    __shared__ int fscan[512];
    int b = blockIdx.x;
    int tid = threadIdx.x;
    int cnt = gtot[b];
    int gs = gstart[b];
    if (tid < 512) fh[tid] = 0;
    __syncthreads();
    for (int i = tid; i < cnt; i += 1024)
        atomicAdd(&fh[grec[gs + i] & 511], 1);
    __syncthreads();
    int v = 0;
    if (tid < 512) { v = fh[tid]; fscan[tid] = v; }
    __syncthreads();
    for (int off = 1; off < 512; off <<= 1) {
        int u = 0;
        if (tid < 512 && tid >= off) u = fscan[tid - off];
        __syncthreads();
        if (tid < 512) fscan[tid] += u;
        __syncthreads();
    }
    if (tid < 512) {
        int excl = fscan[tid] - v;            // exclusive scan value
        int node = (b << BSH) + tid;
        if (node < N_NODES) {
            deg[node] = v;
            dis[node] = rsqrtf((float)v + 1.0f);
            start[node] = gs + excl;
        }
        fh[tid] = excl;                       // -> cursors
    }
    __syncthreads();
    for (int i = tid; i < cnt; i += 1024) {
        unsigned r = grec[gs + i];
        int pos = atomicAdd(&fh[r & 511], 1);
        srcs[gs + pos] = (int)(r >> BSH);
    }
}

// ---- transform-first: hb[row] = bf16( (x @ W^T)[row] * dis[row] ) via bf16 MFMA ----
__global__ __launch_bounds__(256) void k_hx(const float* __restrict__ x,
                                            const __bf16* __restrict__ wb,
                                            const float* __restrict__ dis,
                                            __bf16* __restrict__ hb) {
    int wave = threadIdx.x >> 6;
    int lane = threadIdx.x & 63;
    int strip = blockIdx.x * 4 + wave;
    if (strip >= N_STRIPS) return;
    int m0 = strip * 32;
    int l15 = lane & 15;
    int kq  = lane >> 4;

    bf16x8 a[2][4];
    #pragma unroll
    for (int mt = 0; mt < 2; ++mt) {
        const float* ap = x + (size_t)(m0 + mt * 16 + l15) * D + kq * 8;
        #pragma unroll
        for (int ks = 0; ks < 4; ++ks) {
            float4 lo = *(const float4*)(ap + ks * 32);
            float4 hi = *(const float4*)(ap + ks * 32 + 4);
            bf16x8 t;
            t[0] = (__bf16)lo.x; t[1] = (__bf16)lo.y;
            t[2] = (__bf16)lo.z; t[3] = (__bf16)lo.w;
            t[4] = (__bf16)hi.x; t[5] = (__bf16)hi.y;
            t[6] = (__bf16)hi.z; t[7] = (__bf16)hi.w;
            a[mt][ks] = t;
        }
    }

    f32x4 acc[2][8] = {};
    #pragma unroll
    for (int ks = 0; ks < 4; ++ks) {
        #pragma unroll
        for (int nt = 0; nt < 8; ++nt) {
            bf16x8 b = *(const bf16x8*)(wb + (size_t)(nt * 16 + l15) * D + ks * 32 + kq * 8);
            acc[0][nt] = __builtin_amdgcn_mfma_f32_16x16x32_bf16(a[0][ks], b, acc[0][nt], 0, 0, 0);
            acc[1][nt] = __builtin_amdgcn_mfma_f32_16x16x32_bf16(a[1][ks], b, acc[1][nt], 0, 0, 0);
        }
    }

    float dsv[2][4];
    #pragma unroll
    for (int mt = 0; mt < 2; ++mt)
        #pragma unroll
        for (int r = 0; r < 4; ++r)
            dsv[mt][r] = dis[m0 + mt * 16 + kq * 4 + r];

    #pragma unroll
    for (int nt = 0; nt < 8; ++nt) {
        int colj = nt * 16 + l15;
        #pragma unroll
        for (int mt = 0; mt < 2; ++mt) {
            #pragma unroll
            for (int r = 0; r < 4; ++r) {
                int rowi = m0 + mt * 16 + kq * 4 + r;
                hb[(size_t)rowi * D + colj] = (__bf16)(acc[mt][nt][r] * dsv[mt][r]);
            }
        }
    }
}

// ---- gather-aggregate: one wave per destination, 32 lanes x 8B per row,
// two source rows per VMEM instruction; epilogue adds self term, scales,
// adds bias, relu ----
__global__ __launch_bounds__(256) void k_aggregate(const int* __restrict__ srcs,
                                                   const int* __restrict__ start,
                                                   const int* __restrict__ deg,
                                                   const __bf16* __restrict__ hb,
                                                   const float* __restrict__ dis,
                                                   const float* __restrict__ bias,
                                                   float* __restrict__ out) {
    int node = (blockIdx.x * 256 + threadIdx.x) >> 6;
    int lane = threadIdx.x & 63;
    if (node >= N_NODES) return;
    int li   = lane & 31;          // 8B slot within row (cols 4*li .. 4*li+3)
    int half = lane >> 5;          // which of 2 edges this half-wave handles
    int s = start[node];
    int n = deg[node];
    float dc = dis[node];
    const unsigned char* hbase = (const unsigned char*)hb;
    size_t boff = (size_t)li * 8;

    float acc0 = 0.f, acc1 = 0.f, acc2 = 0.f, acc3 = 0.f;

    for (int base = 0; base < n; base += 64) {
        int m = n - base; if (m > 64) m = 64;
        int src_l = (lane < m) ? srcs[s + base + lane] : 0;
        int i = 0;
        for (; i + 16 <= m; i += 16) {          // 16 edges per batch (8 per half)
            int sv[8]; uint2 av[8];
            #pragma unroll
            for (int j = 0; j < 8; ++j)
                sv[j] = __shfl(src_l, i + 2 * j + half);
            #pragma unroll
            for (int j = 0; j < 8; ++j)
                av[j] = *(const uint2*)(hbase + ((size_t)sv[j] * 256 + boff));
            #pragma unroll
            for (int j = 0; j < 8; ++j) {
                acc0 += __uint_as_float(av[j].x << 16);
                acc1 += __uint_as_float(av[j].x & 0xFFFF0000u);
                acc2 += __uint_as_float(av[j].y << 16);
                acc3 += __uint_as_float(av[j].y & 0xFFFF0000u);
            }
        }
        for (; i + 2 <= m; i += 2) {            // 2 edges per step
            int sj = __shfl(src_l, i + half);
            uint2 a = *(const uint2*)(hbase + ((size_t)sj * 256 + boff));
            acc0 += __uint_as_float(a.x << 16);
            acc1 += __uint_as_float(a.x & 0xFFFF0000u);
            acc2 += __uint_as_float(a.y << 16);
            acc3 += __uint_as_float(a.y & 0xFFFF0000u);
        }
        if (i < m) {                            // odd leftover: half 0 only
            int sj = __shfl(src_l, i);
            if (half == 0) {
                uint2 a = *(const uint2*)(hbase + ((size_t)sj * 256 + boff));
                acc0 += __uint_as_float(a.x << 16);
                acc1 += __uint_as_float(a.x & 0xFFFF0000u);
                acc2 += __uint_as_float(a.y << 16);
                acc3 += __uint_as_float(a.y & 0xFFFF0000u);
            }
        }
    }

    // combine the two halves
    acc0 += __shfl_xor(acc0, 32);
    acc1 += __shfl_xor(acc1, 32);
    acc2 += __shfl_xor(acc2, 32);
    acc3 += __shfl_xor(acc3, 32);

    if (half == 0) {
        // self-loop term (hb already prescaled by dis[node])
        uint2 a = *(const uint2*)(hbase + ((size_t)node * 256 + boff));
        acc0 += __uint_as_float(a.x << 16);
        acc1 += __uint_as_float(a.x & 0xFFFF0000u);
        acc2 += __uint_as_float(a.y << 16);
        acc3 += __uint_as_float(a.y & 0xFFFF0000u);

        float4 b4 = *(const float4*)(bias + li * 4);
        float4 r;
        r.x = fmaxf(acc0 * dc + b4.x, 0.f);
        r.y = fmaxf(acc1 * dc + b4.y, 0.f);
        r.z = fmaxf(acc2 * dc + b4.z, 0.f);
        r.w = fmaxf(acc3 * dc + b4.w, 0.f);
        *(float4*)(out + (size_t)node * D + li * 4) = r;
    }
}

extern "C" void kernel_launch(void* const* d_in, const int* in_sizes, int n_in,
                              void* d_out, int out_size, void* d_ws, size_t ws_size,
                              hipStream_t stream) {
    const float* x    = (const float*)d_in[0];
    const int*   ei   = (const int*)d_in[1];    // [2, E]: row then col
    const float* w    = (const float*)d_in[2];
    const float* bias = (const float*)d_in[3];
    float* out = (float*)d_out;

    char* ws = (char*)d_ws;
    int*      deg    = (int*)ws;              ws += N_NODES * 4;
    float*    dis    = (float*)ws;            ws += N_NODES * 4;
    int*      start  = (int*)ws;              ws += N_NODES * 4;
    int*      bhist  = (int*)ws;              ws += NBKT * P_BLK * 4;
    int*      gtot   = (int*)ws;              ws += 256 * 4;
    int*      gstart = (int*)ws;              ws += 256 * 4;
    __bf16*   wb     = (__bf16*)ws;           ws += D * D * 2;
    unsigned* grec   = (unsigned*)ws;         ws += (size_t)N_EDGES * 4;
    int*      srcs   = (int*)ws;              ws += (size_t)N_EDGES * 4;
    __bf16*   hb     = (__bf16*)ws;           // N_NODES * D * 2 = 25.6 MB

    const int* row = ei;
    const int* col = ei + N_EDGES;

    k_prep     <<<P_BLK + 1, 1024, 0, stream>>>(col, (const float4*)w, bhist, (bf16x4*)wb);
    k_bscan    <<<NBKT, 256, 0, stream>>>(bhist, gtot);
    k_gscan    <<<1, 256, 0, stream>>>(gtot, gstart);
    k_cscatter <<<P_BLK, 1024, 0, stream>>>(row, col, bhist, gstart, grec);
    k_fine     <<<NBKT, 1024, 0, stream>>>(grec, gtot, gstart, deg, dis, start, srcs);
    k_hx       <<<(N_STRIPS + 3) / 4, 256, 0, stream>>>(x, wb, dis, hb);
    k_aggregate<<<(N_NODES * 64 + 255) / 256, 256, 0, stream>>>(srcs, start, deg, hb, dis, bias, out);
}